// Round 7
// baseline (78.413 us; speedup 1.0000x reference)
//
#include <hip/hip_runtime.h>
#include <hip/hip_bf16.h>
#include <cstddef>

// Problem constants: N=100000, E=1600000
constexpr int HID  = 128;
constexpr int OUTW = 32;    // N_CHUNKS * STRU
constexpr int TOT  = 64;    // P outs + Q outs
constexpr int STRU = 4;
constexpr int NCH  = 8;

typedef short  bf16x8 __attribute__((ext_vector_type(8)));
typedef float  f32x4  __attribute__((ext_vector_type(4)));
typedef int    int4v  __attribute__((ext_vector_type(4)));
typedef unsigned short u16x8 __attribute__((ext_vector_type(8)));

__device__ __forceinline__ unsigned short f2bf(float f) {
    unsigned u = __builtin_bit_cast(unsigned, f);
    u += 0x7FFFu + ((u >> 16) & 1u);          // round-to-nearest-even
    return (unsigned short)(u >> 16);
}

__device__ __forceinline__ float dot4(float4 a, float4 b) {
    return a.x * b.x + a.y * b.y + a.z * b.z + a.w * b.w;
}

// bf16 dot of 8 pairs packed in int4v words, accumulated into sum
__device__ __forceinline__ float bfdot(int4v a, int4v b, float sum) {
#pragma unroll
    for (int w = 0; w < 4; ++w) {
        float alo = __builtin_bit_cast(float, (unsigned)(a[w] << 16));
        float ahi = __builtin_bit_cast(float, (unsigned)a[w] & 0xffff0000u);
        float blo = __builtin_bit_cast(float, (unsigned)(b[w] << 16));
        float bhi = __builtin_bit_cast(float, (unsigned)b[w] & 0xffff0000u);
        sum = fmaf(alo, blo, sum);
        sum = fmaf(ahi, bhi, sum);
    }
    return sum;
}

// ---------------------------------------------------------------------------
// Proj (MFMA): per wave 16 nodes x 64 outputs, 4 tiles x 4 K-chunks of
// mfma_f32_16x16x32_bf16. Each block converts the fp32 weights (L2-resident,
// 32KB) directly into fragment-ordered LDS -- no separate prep kernel.
// sW[((t*4+kc)*64+lane)*8+j] = W_row(t*16+(lane&15))[kc*32+(lane>>4)*8+j].
// Epilogue: padded-LDS transpose, coalesced 16B stores to P/Q.
// ---------------------------------------------------------------------------
__global__ __launch_bounds__(256) void proj_mfma(
    const float* __restrict__ x,
    const float* __restrict__ Wq, const float* __restrict__ bq,
    const float* __restrict__ Wv, const float* __restrict__ bv,
    unsigned short* __restrict__ P,
    unsigned short* __restrict__ Q,
    int n_nodes)
{
    __shared__ unsigned short sW[TOT * HID];      // 16 KB, fragment-ordered
    __shared__ unsigned short sPQ[64][TOT + 8];   // 9.2 KB transpose buffer

    const int tid  = threadIdx.x;
    const int wid  = tid >> 6;
    const int lane = tid & 63;
    const int lr   = lane & 15;   // A-row / C-col
    const int lg   = lane >> 4;   // k-group / C row-group
    const int base = blockIdx.x * 64;
    const int m0   = base + wid * 16;

    // ---- issue all x loads first ----
    const int  arow = m0 + lr;
    const bool aok  = arow < n_nodes;
    const float* ap = x + (size_t)arow * HID;

    f32x4 xv[8];
#pragma unroll
    for (int kc = 0; kc < 4; ++kc) {
        if (aok) {
            const f32x4* p = reinterpret_cast<const f32x4*>(ap + kc * 32 + lg * 8);
            xv[2 * kc + 0] = p[0];
            xv[2 * kc + 1] = p[1];
        } else {
            xv[2 * kc + 0] = (f32x4)0.f;
            xv[2 * kc + 1] = (f32x4)0.f;
        }
    }

    // ---- convert weights fp32 -> bf16 fragments in LDS (32 elems/thread) ----
#pragma unroll
    for (int g = 0; g < 4; ++g) {
        int f     = tid * 8 + g * 2048;
        int lane6 = (f >> 3) & 63;
        int kc    = (f >> 9) & 3;
        int t     = f >> 11;
        int o     = t * 16 + (lane6 & 15);
        int k0    = kc * 32 + (lane6 >> 4) * 8;
        const float* wrow = (o < OUTW) ? (Wq + (size_t)o * HID)
                                       : (Wv + (size_t)(o - OUTW) * HID);
        f32x4 w0 = *reinterpret_cast<const f32x4*>(wrow + k0);
        f32x4 w1 = *reinterpret_cast<const f32x4*>(wrow + k0 + 4);
        u16x8 pk;
        pk[0] = f2bf(w0[0]); pk[1] = f2bf(w0[1]); pk[2] = f2bf(w0[2]); pk[3] = f2bf(w0[3]);
        pk[4] = f2bf(w1[0]); pk[5] = f2bf(w1[1]); pk[6] = f2bf(w1[2]); pk[7] = f2bf(w1[3]);
        *reinterpret_cast<u16x8*>(sW + f) = pk;
    }

    // ---- bias into accumulators ----
    f32x4 acc[4];
#pragma unroll
    for (int t = 0; t < 4; ++t) {
        float b = (t < 2) ? bq[t * 16 + lr] : bv[(t - 2) * 16 + lr];
        acc[t][0] = b; acc[t][1] = b; acc[t][2] = b; acc[t][3] = b;
    }

    __syncthreads();

#pragma unroll
    for (int kc = 0; kc < 4; ++kc) {
        f32x4 f0 = xv[2 * kc + 0], f1 = xv[2 * kc + 1];
        bf16x8 a;
        a[0] = (short)f2bf(f0[0]); a[1] = (short)f2bf(f0[1]);
        a[2] = (short)f2bf(f0[2]); a[3] = (short)f2bf(f0[3]);
        a[4] = (short)f2bf(f1[0]); a[5] = (short)f2bf(f1[1]);
        a[6] = (short)f2bf(f1[2]); a[7] = (short)f2bf(f1[3]);
#pragma unroll
        for (int t = 0; t < 4; ++t) {
            bf16x8 bf = *reinterpret_cast<const bf16x8*>(sW + ((size_t)(t * 4 + kc) * 64 + lane) * 8);
            acc[t] = __builtin_amdgcn_mfma_f32_16x16x32_bf16(a, bf, acc[t], 0, 0, 0);
        }
    }

    // ---- epilogue: fragments -> LDS (2B stores, <=2-way alias: free) ----
    const int lrow = wid * 16 + lg * 4;
#pragma unroll
    for (int t = 0; t < 4; ++t)
#pragma unroll
        for (int j = 0; j < 4; ++j)
            sPQ[lrow + j][t * 16 + lr] = f2bf(acc[t][j]);
    __syncthreads();

    // ---- LDS -> global, coalesced: 4 threads/node, 32B each ----
    const int row  = tid >> 2;          // 0..63
    const int q    = tid & 3;           // 0,1 -> P halves; 2,3 -> Q halves
    const int node = base + row;
    if (node < n_nodes) {
        const int scol = q * 16;        // 0,16,32,48
        u16x8 v0 = *reinterpret_cast<const u16x8*>(&sPQ[row][scol]);
        u16x8 v1 = *reinterpret_cast<const u16x8*>(&sPQ[row][scol + 8]);
        unsigned short* dstbase = (q < 2) ? (P + (size_t)node * OUTW + q * 16)
                                          : (Q + (size_t)node * OUTW + (q - 2) * 16);
        u16x8* dst = reinterpret_cast<u16x8*>(dstbase);
        dst[0] = v0;
        dst[1] = v1;
    }
}

// ---------------------------------------------------------------------------
// Edge v2: 2 edges per thread, grid-strided (i and i+G) so index loads and
// output stores remain fully coalesced. launch_bounds(256,1) lets the
// allocator keep all 16 gathers in flight (R4 failed at 36 VGPRs).
// ---------------------------------------------------------------------------
__global__ __launch_bounds__(256, 1) void edge_bf16_x2(
    const int* __restrict__ e,
    const unsigned short* __restrict__ P,
    const unsigned short* __restrict__ Q,
    const float* __restrict__ ratio_p,
    float* __restrict__ out, int E_, int G)
{
    int i0 = blockIdx.x * blockDim.x + threadIdx.x;
    if (i0 >= G) return;
    int i1 = i0 + G;
    const bool has2 = (i1 < E_);

    float scale = (1.0f - ratio_p[0]) * 0.5f;

    int e0a = __builtin_nontemporal_load(e + i0);
    int e1a = __builtin_nontemporal_load(e + E_ + i0);
    int e0b = e0a, e1b = e1a;
    if (has2) {
        e0b = __builtin_nontemporal_load(e + i1);
        e1b = __builtin_nontemporal_load(e + E_ + i1);
    }

    const int4v* pA = reinterpret_cast<const int4v*>(P + (size_t)e0a * OUTW);
    const int4v* qA = reinterpret_cast<const int4v*>(Q + (size_t)e1a * OUTW);
    const int4v* pB = reinterpret_cast<const int4v*>(P + (size_t)e0b * OUTW);
    const int4v* qB = reinterpret_cast<const int4v*>(Q + (size_t)e1b * OUTW);

    // issue all 16 gathers back-to-back
    int4v a0[STRU], b0[STRU], a1[STRU], b1[STRU];
#pragma unroll
    for (int s = 0; s < STRU; ++s) { a0[s] = pA[s]; b0[s] = qA[s]; }
#pragma unroll
    for (int s = 0; s < STRU; ++s) { a1[s] = pB[s]; b1[s] = qB[s]; }

#pragma unroll
    for (int s = 0; s < STRU; ++s) {
        float s0 = bfdot(a0[s], b0[s], 0.f);
        float r0 = 1.0f / (1.0f + __expf(-s0)) * scale + 1.0f;
        __builtin_nontemporal_store(r0, out + (size_t)s * E_ + i0);
        if (has2) {
            float s1 = bfdot(a1[s], b1[s], 0.f);
            float r1 = 1.0f / (1.0f + __expf(-s1)) * scale + 1.0f;
            __builtin_nontemporal_store(r1, out + (size_t)s * E_ + i1);
        }
    }
}

// ---------------------------------------------------------------------------
// Fallback: fully fused per-edge (only if workspace too small).
// ---------------------------------------------------------------------------
__global__ __launch_bounds__(256) void fused_kernel(
    const float* __restrict__ x,
    const int* __restrict__ e,
    const float* __restrict__ ratio_p,
    const float* __restrict__ Wq, const float* __restrict__ bq,
    const float* __restrict__ Wv, const float* __restrict__ bv,
    float* __restrict__ out, int E_)
{
    int i = blockIdx.x * blockDim.x + threadIdx.x;
    if (i >= E_) return;

    float scale = (1.0f - ratio_p[0]) * 0.5f;
    int e0 = e[i];
    int e1 = e[E_ + i];

    const float4* __restrict__ xu  = reinterpret_cast<const float4*>(x + (size_t)e0 * HID);
    const float4* __restrict__ xv_ = reinterpret_cast<const float4*>(x + (size_t)e1 * HID);
    const float4* __restrict__ Wq4 = reinterpret_cast<const float4*>(Wq);
    const float4* __restrict__ Wv4 = reinterpret_cast<const float4*>(Wv);

#pragma unroll 1
    for (int s = 0; s < STRU; ++s) {
        float accP[NCH], accQ[NCH];
#pragma unroll
        for (int c = 0; c < NCH; ++c) { accP[c] = bq[s*NCH+c]; accQ[c] = bv[s*NCH+c]; }
        for (int kc = 0; kc < HID / 4; ++kc) {
            float4 u = xu[kc];
            float4 v = xv_[kc];
#pragma unroll
            for (int c = 0; c < NCH; ++c) {
                int o = s * NCH + c;
                accP[c] += dot4(u, Wq4[o * (HID / 4) + kc]);
                accQ[c] += dot4(v, Wv4[o * (HID / 4) + kc]);
            }
        }
        float sum = 0.0f;
#pragma unroll
        for (int c = 0; c < NCH; ++c) sum += accP[c] * accQ[c];
        float sig = 1.0f / (1.0f + __expf(-sum));
        out[(size_t)s * E_ + i] = sig * scale + 1.0f;
    }
}

extern "C" void kernel_launch(void* const* d_in, const int* in_sizes, int n_in,
                              void* d_out, int out_size, void* d_ws, size_t ws_size,
                              hipStream_t stream)
{
    const float* x     = (const float*)d_in[0];
    const int*   e     = (const int*)  d_in[1];
    const float* ratio = (const float*)d_in[2];
    const float* Wq    = (const float*)d_in[3];
    const float* bq    = (const float*)d_in[4];
    const float* Wv    = (const float*)d_in[5];
    const float* bv    = (const float*)d_in[6];
    float* out = (float*)d_out;

    int N_ = in_sizes[0] / HID;
    int E_ = in_sizes[1] / 2;

    // workspace: P (bf16 N_*32) | Q (bf16 N_*32)
    size_t need = (size_t)N_ * OUTW * 2 * sizeof(unsigned short);
    if (ws_size >= need) {
        unsigned short* P  = (unsigned short*)d_ws;
        unsigned short* Qb = P + (size_t)N_ * OUTW;

        proj_mfma<<<(N_ + 63) / 64, 256, 0, stream>>>(x, Wq, bq, Wv, bv, P, Qb, N_);
        int G = (E_ + 1) / 2;
        edge_bf16_x2<<<(G + 255) / 256, 256, 0, stream>>>(e, P, Qb, ratio, out, E_, G);
    } else {
        fused_kernel<<<(E_ + 255) / 256, 256, 0, stream>>>(x, e, ratio, Wq, bq, Wv, bv, out, E_);
    }
}

// Round 8
// 73.909 us; speedup vs baseline: 1.0609x; 1.0609x over previous
//
#include <hip/hip_runtime.h>
#include <hip/hip_bf16.h>
#include <cstddef>

// Problem constants: N=100000, E=1600000
constexpr int HID  = 128;
constexpr int OUTW = 32;    // N_CHUNKS * STRU
constexpr int TOT  = 64;    // P outs + Q outs
constexpr int STRU = 4;
constexpr int NCH  = 8;

typedef short  bf16x8 __attribute__((ext_vector_type(8)));
typedef float  f32x4  __attribute__((ext_vector_type(4)));
typedef int    int4v  __attribute__((ext_vector_type(4)));
typedef unsigned short u16x8 __attribute__((ext_vector_type(8)));

__device__ __forceinline__ unsigned short f2bf(float f) {
    unsigned u = __builtin_bit_cast(unsigned, f);
    u += 0x7FFFu + ((u >> 16) & 1u);          // round-to-nearest-even
    return (unsigned short)(u >> 16);
}

__device__ __forceinline__ float dot4(float4 a, float4 b) {
    return a.x * b.x + a.y * b.y + a.z * b.z + a.w * b.w;
}

// bf16 dot of 8 pairs packed in int4v words, accumulated into sum
__device__ __forceinline__ float bfdot(int4v a, int4v b, float sum) {
#pragma unroll
    for (int w = 0; w < 4; ++w) {
        float alo = __builtin_bit_cast(float, (unsigned)(a[w] << 16));
        float ahi = __builtin_bit_cast(float, (unsigned)a[w] & 0xffff0000u);
        float blo = __builtin_bit_cast(float, (unsigned)(b[w] << 16));
        float bhi = __builtin_bit_cast(float, (unsigned)b[w] & 0xffff0000u);
        sum = fmaf(alo, blo, sum);
        sum = fmaf(ahi, bhi, sum);
    }
    return sum;
}

// ---------------------------------------------------------------------------
// Proj (MFMA): unchanged from R6 (proven). Per wave 16 nodes x 64 outputs,
// weights converted fp32->bf16 fragment-ordered into LDS per block, MFMA,
// padded-LDS transpose epilogue, coalesced 16B stores to P/Q.
// ---------------------------------------------------------------------------
__global__ __launch_bounds__(256) void proj_mfma(
    const float* __restrict__ x,
    const float* __restrict__ Wq, const float* __restrict__ bq,
    const float* __restrict__ Wv, const float* __restrict__ bv,
    unsigned short* __restrict__ P,
    unsigned short* __restrict__ Q,
    int n_nodes)
{
    __shared__ unsigned short sW[TOT * HID];      // 16 KB, fragment-ordered
    __shared__ unsigned short sPQ[64][TOT + 8];   // 9.2 KB transpose buffer

    const int tid  = threadIdx.x;
    const int wid  = tid >> 6;
    const int lane = tid & 63;
    const int lr   = lane & 15;   // A-row / C-col
    const int lg   = lane >> 4;   // k-group / C row-group
    const int base = blockIdx.x * 64;
    const int m0   = base + wid * 16;

    // ---- issue all x loads first ----
    const int  arow = m0 + lr;
    const bool aok  = arow < n_nodes;
    const float* ap = x + (size_t)arow * HID;

    f32x4 xv[8];
#pragma unroll
    for (int kc = 0; kc < 4; ++kc) {
        if (aok) {
            const f32x4* p = reinterpret_cast<const f32x4*>(ap + kc * 32 + lg * 8);
            xv[2 * kc + 0] = p[0];
            xv[2 * kc + 1] = p[1];
        } else {
            xv[2 * kc + 0] = (f32x4)0.f;
            xv[2 * kc + 1] = (f32x4)0.f;
        }
    }

    // ---- convert weights fp32 -> bf16 fragments in LDS (32 elems/thread) ----
#pragma unroll
    for (int g = 0; g < 4; ++g) {
        int f     = tid * 8 + g * 2048;
        int lane6 = (f >> 3) & 63;
        int kc    = (f >> 9) & 3;
        int t     = f >> 11;
        int o     = t * 16 + (lane6 & 15);
        int k0    = kc * 32 + (lane6 >> 4) * 8;
        const float* wrow = (o < OUTW) ? (Wq + (size_t)o * HID)
                                       : (Wv + (size_t)(o - OUTW) * HID);
        f32x4 w0 = *reinterpret_cast<const f32x4*>(wrow + k0);
        f32x4 w1 = *reinterpret_cast<const f32x4*>(wrow + k0 + 4);
        u16x8 pk;
        pk[0] = f2bf(w0[0]); pk[1] = f2bf(w0[1]); pk[2] = f2bf(w0[2]); pk[3] = f2bf(w0[3]);
        pk[4] = f2bf(w1[0]); pk[5] = f2bf(w1[1]); pk[6] = f2bf(w1[2]); pk[7] = f2bf(w1[3]);
        *reinterpret_cast<u16x8*>(sW + f) = pk;
    }

    // ---- bias into accumulators ----
    f32x4 acc[4];
#pragma unroll
    for (int t = 0; t < 4; ++t) {
        float b = (t < 2) ? bq[t * 16 + lr] : bv[(t - 2) * 16 + lr];
        acc[t][0] = b; acc[t][1] = b; acc[t][2] = b; acc[t][3] = b;
    }

    __syncthreads();

#pragma unroll
    for (int kc = 0; kc < 4; ++kc) {
        f32x4 f0 = xv[2 * kc + 0], f1 = xv[2 * kc + 1];
        bf16x8 a;
        a[0] = (short)f2bf(f0[0]); a[1] = (short)f2bf(f0[1]);
        a[2] = (short)f2bf(f0[2]); a[3] = (short)f2bf(f0[3]);
        a[4] = (short)f2bf(f1[0]); a[5] = (short)f2bf(f1[1]);
        a[6] = (short)f2bf(f1[2]); a[7] = (short)f2bf(f1[3]);
#pragma unroll
        for (int t = 0; t < 4; ++t) {
            bf16x8 bf = *reinterpret_cast<const bf16x8*>(sW + ((size_t)(t * 4 + kc) * 64 + lane) * 8);
            acc[t] = __builtin_amdgcn_mfma_f32_16x16x32_bf16(a, bf, acc[t], 0, 0, 0);
        }
    }

    // ---- epilogue: fragments -> LDS (2B stores, <=2-way alias: free) ----
    const int lrow = wid * 16 + lg * 4;
#pragma unroll
    for (int t = 0; t < 4; ++t)
#pragma unroll
        for (int j = 0; j < 4; ++j)
            sPQ[lrow + j][t * 16 + lr] = f2bf(acc[t][j]);
    __syncthreads();

    // ---- LDS -> global, coalesced: 4 threads/node, 32B each ----
    const int row  = tid >> 2;          // 0..63
    const int q    = tid & 3;           // 0,1 -> P halves; 2,3 -> Q halves
    const int node = base + row;
    if (node < n_nodes) {
        const int scol = q * 16;        // 0,16,32,48
        u16x8 v0 = *reinterpret_cast<const u16x8*>(&sPQ[row][scol]);
        u16x8 v1 = *reinterpret_cast<const u16x8*>(&sPQ[row][scol + 8]);
        unsigned short* dstbase = (q < 2) ? (P + (size_t)node * OUTW + q * 16)
                                          : (Q + (size_t)node * OUTW + (q - 2) * 16);
        u16x8* dst = reinterpret_cast<u16x8*>(dstbase);
        dst[0] = v0;
        dst[1] = v1;
    }
}

// ---------------------------------------------------------------------------
// Edge A (A/B test arm): edges [lo, lo+len), 2 edges/thread (i and i+len/2),
// 16 NAMED int4v gathers + sched_barrier(0) pinning all loads before any
// compute -- forces the allocator to keep the full 64-VGPR payload live
// (true 16-deep MLP; R4/R7 silently serialized at VGPR=32/36).
// ---------------------------------------------------------------------------
__global__ __launch_bounds__(256) void edge_x2f(
    const int* __restrict__ e,
    const unsigned short* __restrict__ P,
    const unsigned short* __restrict__ Q,
    const float* __restrict__ ratio_p,
    float* __restrict__ out, int E_, int lo, int len)
{
    int t  = blockIdx.x * blockDim.x + threadIdx.x;
    int G2 = len >> 1;                 // len is even by construction
    if (t >= G2) return;
    int i0 = lo + t;
    int i1 = i0 + G2;

    float scale = (1.0f - ratio_p[0]) * 0.5f;

    int e0a = __builtin_nontemporal_load(e + i0);
    int e1a = __builtin_nontemporal_load(e + E_ + i0);
    int e0b = __builtin_nontemporal_load(e + i1);
    int e1b = __builtin_nontemporal_load(e + E_ + i1);

    const int4v* pA = reinterpret_cast<const int4v*>(P + (size_t)e0a * OUTW);
    const int4v* qA = reinterpret_cast<const int4v*>(Q + (size_t)e1a * OUTW);
    const int4v* pB = reinterpret_cast<const int4v*>(P + (size_t)e0b * OUTW);
    const int4v* qB = reinterpret_cast<const int4v*>(Q + (size_t)e1b * OUTW);

    // 16 named loads -- all issued before the scheduling barrier
    int4v a0 = pA[0], a1 = pA[1], a2 = pA[2], a3 = pA[3];
    int4v b0 = qA[0], b1 = qA[1], b2 = qA[2], b3 = qA[3];
    int4v c0 = pB[0], c1 = pB[1], c2 = pB[2], c3 = pB[3];
    int4v d0 = qB[0], d1 = qB[1], d2 = qB[2], d3 = qB[3];
    __builtin_amdgcn_sched_barrier(0);

    float s0, r;
    s0 = bfdot(a0, b0, 0.f); r = 1.0f / (1.0f + __expf(-s0)) * scale + 1.0f;
    __builtin_nontemporal_store(r, out + (size_t)0 * E_ + i0);
    s0 = bfdot(a1, b1, 0.f); r = 1.0f / (1.0f + __expf(-s0)) * scale + 1.0f;
    __builtin_nontemporal_store(r, out + (size_t)1 * E_ + i0);
    s0 = bfdot(a2, b2, 0.f); r = 1.0f / (1.0f + __expf(-s0)) * scale + 1.0f;
    __builtin_nontemporal_store(r, out + (size_t)2 * E_ + i0);
    s0 = bfdot(a3, b3, 0.f); r = 1.0f / (1.0f + __expf(-s0)) * scale + 1.0f;
    __builtin_nontemporal_store(r, out + (size_t)3 * E_ + i0);

    s0 = bfdot(c0, d0, 0.f); r = 1.0f / (1.0f + __expf(-s0)) * scale + 1.0f;
    __builtin_nontemporal_store(r, out + (size_t)0 * E_ + i1);
    s0 = bfdot(c1, d1, 0.f); r = 1.0f / (1.0f + __expf(-s0)) * scale + 1.0f;
    __builtin_nontemporal_store(r, out + (size_t)1 * E_ + i1);
    s0 = bfdot(c2, d2, 0.f); r = 1.0f / (1.0f + __expf(-s0)) * scale + 1.0f;
    __builtin_nontemporal_store(r, out + (size_t)2 * E_ + i1);
    s0 = bfdot(c3, d3, 0.f); r = 1.0f / (1.0f + __expf(-s0)) * scale + 1.0f;
    __builtin_nontemporal_store(r, out + (size_t)3 * E_ + i1);
}

// ---------------------------------------------------------------------------
// Edge B (control arm): proven R6 shape, 1 edge/thread, edges [lo, lo+len).
// ---------------------------------------------------------------------------
__global__ __launch_bounds__(256) void edge_bf16(
    const int* __restrict__ e,
    const unsigned short* __restrict__ P,
    const unsigned short* __restrict__ Q,
    const float* __restrict__ ratio_p,
    float* __restrict__ out, int E_, int lo, int len)
{
    int t = blockIdx.x * blockDim.x + threadIdx.x;
    if (t >= len) return;
    int i = lo + t;

    float scale = (1.0f - ratio_p[0]) * 0.5f;
    int e0 = __builtin_nontemporal_load(e + i);
    int e1 = __builtin_nontemporal_load(e + E_ + i);

    const int4v* p4 = reinterpret_cast<const int4v*>(P + (size_t)e0 * OUTW);
    const int4v* q4 = reinterpret_cast<const int4v*>(Q + (size_t)e1 * OUTW);

    int4v a[STRU], b[STRU];
#pragma unroll
    for (int s = 0; s < STRU; ++s) { a[s] = p4[s]; b[s] = q4[s]; }

#pragma unroll
    for (int s = 0; s < STRU; ++s) {
        float sum = bfdot(a[s], b[s], 0.f);
        float sig = 1.0f / (1.0f + __expf(-sum));
        float r   = sig * scale + 1.0f;
        __builtin_nontemporal_store(r, out + (size_t)s * E_ + i);
    }
}

// ---------------------------------------------------------------------------
// Fallback: fully fused per-edge (only if workspace too small).
// ---------------------------------------------------------------------------
__global__ __launch_bounds__(256) void fused_kernel(
    const float* __restrict__ x,
    const int* __restrict__ e,
    const float* __restrict__ ratio_p,
    const float* __restrict__ Wq, const float* __restrict__ bq,
    const float* __restrict__ Wv, const float* __restrict__ bv,
    float* __restrict__ out, int E_)
{
    int i = blockIdx.x * blockDim.x + threadIdx.x;
    if (i >= E_) return;

    float scale = (1.0f - ratio_p[0]) * 0.5f;
    int e0 = e[i];
    int e1 = e[E_ + i];

    const float4* __restrict__ xu  = reinterpret_cast<const float4*>(x + (size_t)e0 * HID);
    const float4* __restrict__ xv_ = reinterpret_cast<const float4*>(x + (size_t)e1 * HID);
    const float4* __restrict__ Wq4 = reinterpret_cast<const float4*>(Wq);
    const float4* __restrict__ Wv4 = reinterpret_cast<const float4*>(Wv);

#pragma unroll 1
    for (int s = 0; s < STRU; ++s) {
        float accP[NCH], accQ[NCH];
#pragma unroll
        for (int c = 0; c < NCH; ++c) { accP[c] = bq[s*NCH+c]; accQ[c] = bv[s*NCH+c]; }
        for (int kc = 0; kc < HID / 4; ++kc) {
            float4 u = xu[kc];
            float4 v = xv_[kc];
#pragma unroll
            for (int c = 0; c < NCH; ++c) {
                int o = s * NCH + c;
                accP[c] += dot4(u, Wq4[o * (HID / 4) + kc]);
                accQ[c] += dot4(v, Wv4[o * (HID / 4) + kc]);
            }
        }
        float sum = 0.0f;
#pragma unroll
        for (int c = 0; c < NCH; ++c) sum += accP[c] * accQ[c];
        float sig = 1.0f / (1.0f + __expf(-sum));
        out[(size_t)s * E_ + i] = sig * scale + 1.0f;
    }
}

extern "C" void kernel_launch(void* const* d_in, const int* in_sizes, int n_in,
                              void* d_out, int out_size, void* d_ws, size_t ws_size,
                              hipStream_t stream)
{
    const float* x     = (const float*)d_in[0];
    const int*   e     = (const int*)  d_in[1];
    const float* ratio = (const float*)d_in[2];
    const float* Wq    = (const float*)d_in[3];
    const float* bq    = (const float*)d_in[4];
    const float* Wv    = (const float*)d_in[5];
    const float* bv    = (const float*)d_in[6];
    float* out = (float*)d_out;

    int N_ = in_sizes[0] / HID;
    int E_ = in_sizes[1] / 2;

    // workspace: P (bf16 N_*32) | Q (bf16 N_*32)
    size_t need = (size_t)N_ * OUTW * 2 * sizeof(unsigned short);
    if (ws_size >= need) {
        unsigned short* P  = (unsigned short*)d_ws;
        unsigned short* Qb = P + (size_t)N_ * OUTW;

        proj_mfma<<<(N_ + 63) / 64, 256, 0, stream>>>(x, Wq, bq, Wv, bv, P, Qb, N_);

        int half = (E_ / 2) & ~1;      // even length for the x2 arm
        if (half >= 2) {
            int G2 = half / 2;
            edge_x2f<<<(G2 + 255) / 256, 256, 0, stream>>>(e, P, Qb, ratio, out, E_, 0, half);
            int rem = E_ - half;
            if (rem > 0)
                edge_bf16<<<(rem + 255) / 256, 256, 0, stream>>>(e, P, Qb, ratio, out, E_, half, rem);
        } else {
            edge_bf16<<<(E_ + 255) / 256, 256, 0, stream>>>(e, P, Qb, ratio, out, E_, 0, E_);
        }
    } else {
        fused_kernel<<<(E_ + 255) / 256, 256, 0, stream>>>(x, e, ratio, Wq, bq, Wv, bv, out, E_);
    }
}

// Round 9
// 68.792 us; speedup vs baseline: 1.1399x; 1.0744x over previous
//
#include <hip/hip_runtime.h>
#include <hip/hip_bf16.h>
#include <cstddef>

// Problem constants: N=100000, E=1600000
constexpr int HID  = 128;
constexpr int OUTW = 32;    // N_CHUNKS * STRU
constexpr int TOT  = 64;    // P outs + Q outs
constexpr int STRU = 4;
constexpr int NCH  = 8;
constexpr int NB   = 128;   // nodes per proj block

typedef short  bf16x8 __attribute__((ext_vector_type(8)));
typedef float  f32x4  __attribute__((ext_vector_type(4)));
typedef int    int4v  __attribute__((ext_vector_type(4)));
typedef unsigned short u16x8 __attribute__((ext_vector_type(8)));

__device__ __forceinline__ unsigned short f2bf(float f) {
    unsigned u = __builtin_bit_cast(unsigned, f);
    u += 0x7FFFu + ((u >> 16) & 1u);          // round-to-nearest-even
    return (unsigned short)(u >> 16);
}

__device__ __forceinline__ float dot4(float4 a, float4 b) {
    return a.x * b.x + a.y * b.y + a.z * b.z + a.w * b.w;
}

// bf16 dot of 8 pairs packed in int4v words, accumulated into sum
__device__ __forceinline__ float bfdot(int4v a, int4v b, float sum) {
#pragma unroll
    for (int w = 0; w < 4; ++w) {
        float alo = __builtin_bit_cast(float, (unsigned)(a[w] << 16));
        float ahi = __builtin_bit_cast(float, (unsigned)a[w] & 0xffff0000u);
        float blo = __builtin_bit_cast(float, (unsigned)(b[w] << 16));
        float bhi = __builtin_bit_cast(float, (unsigned)b[w] & 0xffff0000u);
        sum = fmaf(alo, blo, sum);
        sum = fmaf(ahi, bhi, sum);
    }
    return sum;
}

// ---------------------------------------------------------------------------
// Proj (MFMA): 128 nodes/block, 512 threads (8 waves x 16 nodes -- per-wave
// shape identical to the proven R6 kernel). Weights converted fp32->bf16
// fragment-ordered into LDS once per block (2x fewer blocks than R6 -> half
// the weight-conversion overhead). LDS 34.8 KB -> 4 blocks/CU (full 2048
// threads/CU). Epilogue: padded-LDS transpose, coalesced 16B stores.
// ---------------------------------------------------------------------------
__global__ __launch_bounds__(512) void proj_mfma(
    const float* __restrict__ x,
    const float* __restrict__ Wq, const float* __restrict__ bq,
    const float* __restrict__ Wv, const float* __restrict__ bv,
    unsigned short* __restrict__ P,
    unsigned short* __restrict__ Q,
    int n_nodes)
{
    __shared__ unsigned short sW[TOT * HID];      // 16 KB, fragment-ordered
    __shared__ unsigned short sPQ[NB][TOT + 8];   // 18.4 KB transpose buffer

    const int tid  = threadIdx.x;
    const int wid  = tid >> 6;    // 0..7
    const int lane = tid & 63;
    const int lr   = lane & 15;   // A-row / C-col
    const int lg   = lane >> 4;   // k-group / C row-group
    const int base = blockIdx.x * NB;
    const int m0   = base + wid * 16;

    // ---- issue all x loads first ----
    const int  arow = m0 + lr;
    const bool aok  = arow < n_nodes;
    const float* ap = x + (size_t)arow * HID;

    f32x4 xv[8];
#pragma unroll
    for (int kc = 0; kc < 4; ++kc) {
        if (aok) {
            const f32x4* p = reinterpret_cast<const f32x4*>(ap + kc * 32 + lg * 8);
            xv[2 * kc + 0] = p[0];
            xv[2 * kc + 1] = p[1];
        } else {
            xv[2 * kc + 0] = (f32x4)0.f;
            xv[2 * kc + 1] = (f32x4)0.f;
        }
    }

    // ---- convert weights fp32 -> bf16 fragments in LDS (16 elems/thread) ----
#pragma unroll
    for (int g = 0; g < 2; ++g) {
        int f     = tid * 8 + g * 4096;
        int lane6 = (f >> 3) & 63;
        int kc    = (f >> 9) & 3;
        int t     = f >> 11;
        int o     = t * 16 + (lane6 & 15);
        int k0    = kc * 32 + (lane6 >> 4) * 8;
        const float* wrow = (o < OUTW) ? (Wq + (size_t)o * HID)
                                       : (Wv + (size_t)(o - OUTW) * HID);
        f32x4 w0 = *reinterpret_cast<const f32x4*>(wrow + k0);
        f32x4 w1 = *reinterpret_cast<const f32x4*>(wrow + k0 + 4);
        u16x8 pk;
        pk[0] = f2bf(w0[0]); pk[1] = f2bf(w0[1]); pk[2] = f2bf(w0[2]); pk[3] = f2bf(w0[3]);
        pk[4] = f2bf(w1[0]); pk[5] = f2bf(w1[1]); pk[6] = f2bf(w1[2]); pk[7] = f2bf(w1[3]);
        *reinterpret_cast<u16x8*>(sW + f) = pk;
    }

    // ---- bias into accumulators ----
    f32x4 acc[4];
#pragma unroll
    for (int t = 0; t < 4; ++t) {
        float b = (t < 2) ? bq[t * 16 + lr] : bv[(t - 2) * 16 + lr];
        acc[t][0] = b; acc[t][1] = b; acc[t][2] = b; acc[t][3] = b;
    }

    __syncthreads();

#pragma unroll
    for (int kc = 0; kc < 4; ++kc) {
        f32x4 f0 = xv[2 * kc + 0], f1 = xv[2 * kc + 1];
        bf16x8 a;
        a[0] = (short)f2bf(f0[0]); a[1] = (short)f2bf(f0[1]);
        a[2] = (short)f2bf(f0[2]); a[3] = (short)f2bf(f0[3]);
        a[4] = (short)f2bf(f1[0]); a[5] = (short)f2bf(f1[1]);
        a[6] = (short)f2bf(f1[2]); a[7] = (short)f2bf(f1[3]);
#pragma unroll
        for (int t = 0; t < 4; ++t) {
            bf16x8 bf = *reinterpret_cast<const bf16x8*>(sW + ((size_t)(t * 4 + kc) * 64 + lane) * 8);
            acc[t] = __builtin_amdgcn_mfma_f32_16x16x32_bf16(a, bf, acc[t], 0, 0, 0);
        }
    }

    // ---- epilogue: fragments -> LDS (2B stores, <=2-way alias: free) ----
    const int lrow = wid * 16 + lg * 4;
#pragma unroll
    for (int t = 0; t < 4; ++t)
#pragma unroll
        for (int j = 0; j < 4; ++j)
            sPQ[lrow + j][t * 16 + lr] = f2bf(acc[t][j]);
    __syncthreads();

    // ---- LDS -> global, coalesced: 4 threads/node, 32B each ----
    const int row  = tid >> 2;          // 0..127
    const int q    = tid & 3;           // 0,1 -> P halves; 2,3 -> Q halves
    const int node = base + row;
    if (node < n_nodes) {
        const int scol = q * 16;        // 0,16,32,48
        u16x8 v0 = *reinterpret_cast<const u16x8*>(&sPQ[row][scol]);
        u16x8 v1 = *reinterpret_cast<const u16x8*>(&sPQ[row][scol + 8]);
        unsigned short* dstbase = (q < 2) ? (P + (size_t)node * OUTW + q * 16)
                                          : (Q + (size_t)node * OUTW + (q - 2) * 16);
        u16x8* dst = reinterpret_cast<u16x8*>(dstbase);
        dst[0] = v0;
        dst[1] = v1;
    }
}

// ---------------------------------------------------------------------------
// Edge: proven R6 shape (1 edge/thread, 8x16B gathers, nt index/store).
// Fabric/L2-bound at ~46us -- R4/R7/R8 A/B showed deeper per-thread MLP
// does NOT help; do not revisit.
// ---------------------------------------------------------------------------
__global__ __launch_bounds__(256) void edge_bf16(
    const int* __restrict__ e,
    const unsigned short* __restrict__ P,
    const unsigned short* __restrict__ Q,
    const float* __restrict__ ratio_p,
    float* __restrict__ out, int E_)
{
    int i = blockIdx.x * blockDim.x + threadIdx.x;
    if (i >= E_) return;

    float scale = (1.0f - ratio_p[0]) * 0.5f;
    int e0 = __builtin_nontemporal_load(e + i);
    int e1 = __builtin_nontemporal_load(e + E_ + i);

    const int4v* p4 = reinterpret_cast<const int4v*>(P + (size_t)e0 * OUTW);
    const int4v* q4 = reinterpret_cast<const int4v*>(Q + (size_t)e1 * OUTW);

    int4v a[STRU], b[STRU];
#pragma unroll
    for (int s = 0; s < STRU; ++s) { a[s] = p4[s]; b[s] = q4[s]; }

#pragma unroll
    for (int s = 0; s < STRU; ++s) {
        float sum = bfdot(a[s], b[s], 0.f);
        float sig = 1.0f / (1.0f + __expf(-sum));
        float r   = sig * scale + 1.0f;
        __builtin_nontemporal_store(r, out + (size_t)s * E_ + i);
    }
}

// ---------------------------------------------------------------------------
// Fallback: fully fused per-edge (only if workspace too small).
// ---------------------------------------------------------------------------
__global__ __launch_bounds__(256) void fused_kernel(
    const float* __restrict__ x,
    const int* __restrict__ e,
    const float* __restrict__ ratio_p,
    const float* __restrict__ Wq, const float* __restrict__ bq,
    const float* __restrict__ Wv, const float* __restrict__ bv,
    float* __restrict__ out, int E_)
{
    int i = blockIdx.x * blockDim.x + threadIdx.x;
    if (i >= E_) return;

    float scale = (1.0f - ratio_p[0]) * 0.5f;
    int e0 = e[i];
    int e1 = e[E_ + i];

    const float4* __restrict__ xu  = reinterpret_cast<const float4*>(x + (size_t)e0 * HID);
    const float4* __restrict__ xv_ = reinterpret_cast<const float4*>(x + (size_t)e1 * HID);
    const float4* __restrict__ Wq4 = reinterpret_cast<const float4*>(Wq);
    const float4* __restrict__ Wv4 = reinterpret_cast<const float4*>(Wv);

#pragma unroll 1
    for (int s = 0; s < STRU; ++s) {
        float accP[NCH], accQ[NCH];
#pragma unroll
        for (int c = 0; c < NCH; ++c) { accP[c] = bq[s*NCH+c]; accQ[c] = bv[s*NCH+c]; }
        for (int kc = 0; kc < HID / 4; ++kc) {
            float4 u = xu[kc];
            float4 v = xv_[kc];
#pragma unroll
            for (int c = 0; c < NCH; ++c) {
                int o = s * NCH + c;
                accP[c] += dot4(u, Wq4[o * (HID / 4) + kc]);
                accQ[c] += dot4(v, Wv4[o * (HID / 4) + kc]);
            }
        }
        float sum = 0.0f;
#pragma unroll
        for (int c = 0; c < NCH; ++c) sum += accP[c] * accQ[c];
        float sig = 1.0f / (1.0f + __expf(-sum));
        out[(size_t)s * E_ + i] = sig * scale + 1.0f;
    }
}

extern "C" void kernel_launch(void* const* d_in, const int* in_sizes, int n_in,
                              void* d_out, int out_size, void* d_ws, size_t ws_size,
                              hipStream_t stream)
{
    const float* x     = (const float*)d_in[0];
    const int*   e     = (const int*)  d_in[1];
    const float* ratio = (const float*)d_in[2];
    const float* Wq    = (const float*)d_in[3];
    const float* bq    = (const float*)d_in[4];
    const float* Wv    = (const float*)d_in[5];
    const float* bv    = (const float*)d_in[6];
    float* out = (float*)d_out;

    int N_ = in_sizes[0] / HID;
    int E_ = in_sizes[1] / 2;

    // workspace: P (bf16 N_*32) | Q (bf16 N_*32)
    size_t need = (size_t)N_ * OUTW * 2 * sizeof(unsigned short);
    if (ws_size >= need) {
        unsigned short* P  = (unsigned short*)d_ws;
        unsigned short* Qb = P + (size_t)N_ * OUTW;

        proj_mfma<<<(N_ + NB - 1) / NB, 512, 0, stream>>>(x, Wq, bq, Wv, bv, P, Qb, N_);
        edge_bf16<<<(E_ + 255) / 256, 256, 0, stream>>>(e, P, Qb, ratio, out, E_);
    } else {
        fused_kernel<<<(E_ + 255) / 256, 256, 0, stream>>>(x, e, ratio, Wq, bq, Wv, bv, out, E_);
    }
}

// Round 10
// 67.331 us; speedup vs baseline: 1.1646x; 1.0217x over previous
//
#include <hip/hip_runtime.h>
#include <hip/hip_bf16.h>
#include <cstddef>

// Problem constants: N=100000, E=1600000
constexpr int HID  = 128;
constexpr int OUTW = 32;    // N_CHUNKS * STRU
constexpr int TOT  = 64;    // P outs + Q outs
constexpr int STRU = 4;
constexpr int NCH  = 8;

typedef short  bf16x8 __attribute__((ext_vector_type(8)));
typedef float  f32x4  __attribute__((ext_vector_type(4)));
typedef int    int4v  __attribute__((ext_vector_type(4)));
typedef unsigned short u16x8 __attribute__((ext_vector_type(8)));

__device__ __forceinline__ unsigned short f2bf(float f) {
    unsigned u = __builtin_bit_cast(unsigned, f);
    u += 0x7FFFu + ((u >> 16) & 1u);          // round-to-nearest-even
    return (unsigned short)(u >> 16);
}

__device__ __forceinline__ float dot4(float4 a, float4 b) {
    return a.x * b.x + a.y * b.y + a.z * b.z + a.w * b.w;
}

// bf16 dot of 8 pairs packed in int4v words, accumulated into sum
__device__ __forceinline__ float bfdot(int4v a, int4v b, float sum) {
#pragma unroll
    for (int w = 0; w < 4; ++w) {
        float alo = __builtin_bit_cast(float, (unsigned)(a[w] << 16));
        float ahi = __builtin_bit_cast(float, (unsigned)a[w] & 0xffff0000u);
        float blo = __builtin_bit_cast(float, (unsigned)(b[w] << 16));
        float bhi = __builtin_bit_cast(float, (unsigned)b[w] & 0xffff0000u);
        sum = fmaf(alo, blo, sum);
        sum = fmaf(ahi, bhi, sum);
    }
    return sum;
}

// ---------------------------------------------------------------------------
// Proj (MFMA): 2 node-tiles (2x64 nodes) per 256-thread block. ALL x loads
// for both tiles issued up-front (16 x 16B = 256B/thread outstanding -> 2x
// the MLP depth of R9; proj is a single-occupancy-round kernel so duration
// is one block's latency chain). sW converted once per block, amortized
// over both tiles. LDS 25.2 KB -> 6 blocks/CU.
// ---------------------------------------------------------------------------
__global__ __launch_bounds__(256) void proj_mfma(
    const float* __restrict__ x,
    const float* __restrict__ Wq, const float* __restrict__ bq,
    const float* __restrict__ Wv, const float* __restrict__ bv,
    unsigned short* __restrict__ P,
    unsigned short* __restrict__ Q,
    int n_nodes)
{
    __shared__ unsigned short sW[TOT * HID];      // 16 KB, fragment-ordered
    __shared__ unsigned short sPQ[64][TOT + 8];   // 9.2 KB transpose buffer

    const int tid  = threadIdx.x;
    const int wid  = tid >> 6;
    const int lane = tid & 63;
    const int lr   = lane & 15;   // A-row / C-col
    const int lg   = lane >> 4;   // k-group / C row-group

    const int bases[2] = { (int)blockIdx.x * 64,
                           (int)(blockIdx.x + gridDim.x) * 64 };

    // ---- issue ALL x loads for both tiles first (16 outstanding 16B) ----
    f32x4 xv[2][8];
#pragma unroll
    for (int it = 0; it < 2; ++it) {
        const int  arow = bases[it] + wid * 16 + lr;
        const bool aok  = arow < n_nodes;
        const float* ap = x + (size_t)arow * HID;
#pragma unroll
        for (int kc = 0; kc < 4; ++kc) {
            if (aok) {
                const f32x4* p = reinterpret_cast<const f32x4*>(ap + kc * 32 + lg * 8);
                xv[it][2 * kc + 0] = p[0];
                xv[it][2 * kc + 1] = p[1];
            } else {
                xv[it][2 * kc + 0] = (f32x4)0.f;
                xv[it][2 * kc + 1] = (f32x4)0.f;
            }
        }
    }

    // ---- convert weights fp32 -> bf16 fragments in LDS (32 elems/thread) ----
#pragma unroll
    for (int g = 0; g < 4; ++g) {
        int f     = tid * 8 + g * 2048;
        int lane6 = (f >> 3) & 63;
        int kc    = (f >> 9) & 3;
        int t     = f >> 11;
        int o     = t * 16 + (lane6 & 15);
        int k0    = kc * 32 + (lane6 >> 4) * 8;
        const float* wrow = (o < OUTW) ? (Wq + (size_t)o * HID)
                                       : (Wv + (size_t)(o - OUTW) * HID);
        f32x4 w0 = *reinterpret_cast<const f32x4*>(wrow + k0);
        f32x4 w1 = *reinterpret_cast<const f32x4*>(wrow + k0 + 4);
        u16x8 pk;
        pk[0] = f2bf(w0[0]); pk[1] = f2bf(w0[1]); pk[2] = f2bf(w0[2]); pk[3] = f2bf(w0[3]);
        pk[4] = f2bf(w1[0]); pk[5] = f2bf(w1[1]); pk[6] = f2bf(w1[2]); pk[7] = f2bf(w1[3]);
        *reinterpret_cast<u16x8*>(sW + f) = pk;
    }

    __syncthreads();   // sW ready

#pragma unroll
    for (int it = 0; it < 2; ++it) {
        const int base = bases[it];

        // ---- bias into accumulators ----
        f32x4 acc[4];
#pragma unroll
        for (int t = 0; t < 4; ++t) {
            float b = (t < 2) ? bq[t * 16 + lr] : bv[(t - 2) * 16 + lr];
            acc[t][0] = b; acc[t][1] = b; acc[t][2] = b; acc[t][3] = b;
        }

#pragma unroll
        for (int kc = 0; kc < 4; ++kc) {
            f32x4 f0 = xv[it][2 * kc + 0], f1 = xv[it][2 * kc + 1];
            bf16x8 a;
            a[0] = (short)f2bf(f0[0]); a[1] = (short)f2bf(f0[1]);
            a[2] = (short)f2bf(f0[2]); a[3] = (short)f2bf(f0[3]);
            a[4] = (short)f2bf(f1[0]); a[5] = (short)f2bf(f1[1]);
            a[6] = (short)f2bf(f1[2]); a[7] = (short)f2bf(f1[3]);
#pragma unroll
            for (int t = 0; t < 4; ++t) {
                bf16x8 bf = *reinterpret_cast<const bf16x8*>(
                    sW + ((size_t)(t * 4 + kc) * 64 + lane) * 8);
                acc[t] = __builtin_amdgcn_mfma_f32_16x16x32_bf16(a, bf, acc[t], 0, 0, 0);
            }
        }

        if (it) __syncthreads();   // previous tile's sPQ reads complete

        // ---- fragments -> LDS (2B stores, <=2-way alias: free) ----
        const int lrow = wid * 16 + lg * 4;
#pragma unroll
        for (int t = 0; t < 4; ++t)
#pragma unroll
            for (int j = 0; j < 4; ++j)
                sPQ[lrow + j][t * 16 + lr] = f2bf(acc[t][j]);
        __syncthreads();

        // ---- LDS -> global, coalesced: 4 threads/node, 32B each ----
        const int row  = tid >> 2;          // 0..63
        const int q    = tid & 3;           // 0,1 -> P halves; 2,3 -> Q halves
        const int node = base + row;
        if (node < n_nodes) {
            const int scol = q * 16;        // 0,16,32,48
            u16x8 v0 = *reinterpret_cast<const u16x8*>(&sPQ[row][scol]);
            u16x8 v1 = *reinterpret_cast<const u16x8*>(&sPQ[row][scol + 8]);
            unsigned short* dstbase = (q < 2) ? (P + (size_t)node * OUTW + q * 16)
                                              : (Q + (size_t)node * OUTW + (q - 2) * 16);
            u16x8* dst = reinterpret_cast<u16x8*>(dstbase);
            dst[0] = v0;
            dst[1] = v1;
        }
    }
}

// ---------------------------------------------------------------------------
// Edge: proven R6 shape (1 edge/thread, 8x16B gathers, nt index/store).
// Fabric/L2-bound at ~46us -- R4/R7/R8 A/B showed deeper per-thread MLP
// does NOT help; do not revisit.
// ---------------------------------------------------------------------------
__global__ __launch_bounds__(256) void edge_bf16(
    const int* __restrict__ e,
    const unsigned short* __restrict__ P,
    const unsigned short* __restrict__ Q,
    const float* __restrict__ ratio_p,
    float* __restrict__ out, int E_)
{
    int i = blockIdx.x * blockDim.x + threadIdx.x;
    if (i >= E_) return;

    float scale = (1.0f - ratio_p[0]) * 0.5f;
    int e0 = __builtin_nontemporal_load(e + i);
    int e1 = __builtin_nontemporal_load(e + E_ + i);

    const int4v* p4 = reinterpret_cast<const int4v*>(P + (size_t)e0 * OUTW);
    const int4v* q4 = reinterpret_cast<const int4v*>(Q + (size_t)e1 * OUTW);

    int4v a[STRU], b[STRU];
#pragma unroll
    for (int s = 0; s < STRU; ++s) { a[s] = p4[s]; b[s] = q4[s]; }

#pragma unroll
    for (int s = 0; s < STRU; ++s) {
        float sum = bfdot(a[s], b[s], 0.f);
        float sig = 1.0f / (1.0f + __expf(-sum));
        float r   = sig * scale + 1.0f;
        __builtin_nontemporal_store(r, out + (size_t)s * E_ + i);
    }
}

// ---------------------------------------------------------------------------
// Fallback: fully fused per-edge (only if workspace too small).
// ---------------------------------------------------------------------------
__global__ __launch_bounds__(256) void fused_kernel(
    const float* __restrict__ x,
    const int* __restrict__ e,
    const float* __restrict__ ratio_p,
    const float* __restrict__ Wq, const float* __restrict__ bq,
    const float* __restrict__ Wv, const float* __restrict__ bv,
    float* __restrict__ out, int E_)
{
    int i = blockIdx.x * blockDim.x + threadIdx.x;
    if (i >= E_) return;

    float scale = (1.0f - ratio_p[0]) * 0.5f;
    int e0 = e[i];
    int e1 = e[E_ + i];

    const float4* __restrict__ xu  = reinterpret_cast<const float4*>(x + (size_t)e0 * HID);
    const float4* __restrict__ xv_ = reinterpret_cast<const float4*>(x + (size_t)e1 * HID);
    const float4* __restrict__ Wq4 = reinterpret_cast<const float4*>(Wq);
    const float4* __restrict__ Wv4 = reinterpret_cast<const float4*>(Wv);

#pragma unroll 1
    for (int s = 0; s < STRU; ++s) {
        float accP[NCH], accQ[NCH];
#pragma unroll
        for (int c = 0; c < NCH; ++c) { accP[c] = bq[s*NCH+c]; accQ[c] = bv[s*NCH+c]; }
        for (int kc = 0; kc < HID / 4; ++kc) {
            float4 u = xu[kc];
            float4 v = xv_[kc];
#pragma unroll
            for (int c = 0; c < NCH; ++c) {
                int o = s * NCH + c;
                accP[c] += dot4(u, Wq4[o * (HID / 4) + kc]);
                accQ[c] += dot4(v, Wv4[o * (HID / 4) + kc]);
            }
        }
        float sum = 0.0f;
#pragma unroll
        for (int c = 0; c < NCH; ++c) sum += accP[c] * accQ[c];
        float sig = 1.0f / (1.0f + __expf(-sum));
        out[(size_t)s * E_ + i] = sig * scale + 1.0f;
    }
}

extern "C" void kernel_launch(void* const* d_in, const int* in_sizes, int n_in,
                              void* d_out, int out_size, void* d_ws, size_t ws_size,
                              hipStream_t stream)
{
    const float* x     = (const float*)d_in[0];
    const int*   e     = (const int*)  d_in[1];
    const float* ratio = (const float*)d_in[2];
    const float* Wq    = (const float*)d_in[3];
    const float* bq    = (const float*)d_in[4];
    const float* Wv    = (const float*)d_in[5];
    const float* bv    = (const float*)d_in[6];
    float* out = (float*)d_out;

    int N_ = in_sizes[0] / HID;
    int E_ = in_sizes[1] / 2;

    // workspace: P (bf16 N_*32) | Q (bf16 N_*32)
    size_t need = (size_t)N_ * OUTW * 2 * sizeof(unsigned short);
    if (ws_size >= need) {
        unsigned short* P  = (unsigned short*)d_ws;
        unsigned short* Qb = P + (size_t)N_ * OUTW;

        int ntiles = (N_ + 63) / 64;
        int grid   = (ntiles + 1) / 2;   // 2 tiles per block
        proj_mfma<<<grid, 256, 0, stream>>>(x, Wq, bq, Wv, bv, P, Qb, N_);
        edge_bf16<<<(E_ + 255) / 256, 256, 0, stream>>>(e, P, Qb, ratio, out, E_);
    } else {
        fused_kernel<<<(E_ + 255) / 256, 256, 0, stream>>>(x, e, ratio, Wq, bq, Wv, bv, out, E_);
    }
}